// Round 4
// baseline (35.533 us; speedup 1.0000x reference)
//
#include <hip/hip_runtime.h>

typedef __attribute__((ext_vector_type(8))) short bf16x8;
typedef __attribute__((ext_vector_type(4))) float f32x4;

#define PATCHES 196
#define ROWS 588             // 196 patches * 3 channels
#define NCHUNK 10            // ceil(588/64) row-chunks per batch
#define SCORE_B_STRIDE 5376  // 128*3*14 floats

// pack two f32 -> two bf16 (RNE) in one u32
static __device__ __forceinline__ unsigned f2bf2(float a, float b) {
    union { float f; unsigned u; } x, y; x.f = a; y.f = b;
    unsigned lo = (x.u + 0x7FFFu + ((x.u >> 16) & 1u)) >> 16;
    unsigned hi = (y.u + 0x7FFFu + ((y.u >> 16) & 1u)) & 0xFFFF0000u;
    return lo | hi;
}

// ---------------- Kernel 1: BM workspace, layout [b][k>>3][mn][8k] bf16 -------
__global__ __launch_bounds__(256) void bm_build(
    const float* __restrict__ h_base,   // [B,128,16]
    const float* __restrict__ v_base,   // [B,128,16]
    uint4* __restrict__ bmv)
{
    __shared__ float hbT[16][68];   // [m][k'] pad->stride 68: 2-way conflicts only
    __shared__ float vbT[16][68];
    const int b = blockIdx.x, zb = blockIdx.y, t = threadIdx.x;
    const float* hg = h_base + (size_t)b * 2048 + zb * 1024;
    const float* vg = v_base + (size_t)b * 2048 + zb * 1024;
#pragma unroll
    for (int i = 0; i < 4; ++i) {
        const int idx = t + i * 256;        // k' = idx>>4, m = idx&15
        hbT[idx & 15][idx >> 4] = hg[idx];
        vbT[idx & 15][idx >> 4] = vg[idx];
    }
    __syncthreads();

    const int m = t >> 4, n = t & 15;       // mn = t
    uint4* dst = bmv + ((size_t)b * 16 + zb * 8) * 256 + t;
#pragma unroll
    for (int i = 0; i < 8; ++i) {
        const float* vp = &vbT[m][i * 8];
        const float* hp = &hbT[n][i * 8];
        float p[8];
#pragma unroll
        for (int j = 0; j < 8; ++j) p[j] = vp[j] * hp[j];
        uint4 u = { f2bf2(p[0],p[1]), f2bf2(p[2],p[3]),
                    f2bf2(p[4],p[5]), f2bf2(p[6],p[7]) };
        dst[i * 256] = u;                   // 1KB coalesced, stays L2-hot
    }
}

// ---------------- Kernel 2: fused softmax-W (LDS) + MFMA GEMM (B from L2) -----
__global__ __launch_bounds__(256, 3) void patch_gemm(
    const float* __restrict__ h_scores, // [B,128,3,14]
    const float* __restrict__ v_score,  // [B,128,3,14]
    const uint4* __restrict__ bmv,
    float* __restrict__ out)            // [B,588,256]
{
    __shared__ __align__(16) char lds[16384];   // W: 64 rows x 256B, XOR-swizzled

    const int bid = blockIdx.x;
    const int xcd = bid & 7, rest = bid >> 3;   // bijective: b%8 == XCD == k1 writer
    const int b = (rest / NCHUNK) * 8 + xcd;
    const int chunk = rest % NCHUNK;
    const int t = threadIdx.x;

    // ---- softmax weights: thread = (row r = t>>2, k-quarter kq = t&3) ----
    {
        const int r = t >> 2, kq = t & 3;
        const int grow = chunk * 64 + r;
        const int geff = grow < ROWS ? grow : ROWS - 1;  // clamp; masked at store
        const int p = geff / 3, c = geff - p * 3;
        const int np = p / 14, mp = p - np * 14;
        const float* hsb = h_scores + (size_t)b * SCORE_B_STRIDE;
        const float* vsb = v_score  + (size_t)b * SCORE_B_STRIDE;
        const int hix = c * 14 + np, vix = c * 14 + mp;

        float sc[32];
#pragma unroll
        for (int j = 0; j < 32; ++j) {
            const int k = kq * 32 + j;
            sc[j] = hsb[k * 42 + hix] * vsb[k * 42 + vix];
        }
        float mx = sc[0];
#pragma unroll
        for (int j = 1; j < 32; ++j) mx = fmaxf(mx, sc[j]);
        mx = fmaxf(mx, __shfl_xor(mx, 1));
        mx = fmaxf(mx, __shfl_xor(mx, 2));
        float sum = 0.f;
#pragma unroll
        for (int j = 0; j < 32; ++j) { sc[j] = __expf(sc[j] - mx); sum += sc[j]; }
        sum += __shfl_xor(sum, 1);
        sum += __shfl_xor(sum, 2);
        const float inv = 1.f / sum;

        const int sw = (r & 7) << 4;
#pragma unroll
        for (int s2 = 0; s2 < 4; ++s2) {
            const int kpos = (kq * 32 + s2 * 8) * 2;     // byte offset of k0
            uint4 u = { f2bf2(sc[s2*8+0]*inv, sc[s2*8+1]*inv),
                        f2bf2(sc[s2*8+2]*inv, sc[s2*8+3]*inv),
                        f2bf2(sc[s2*8+4]*inv, sc[s2*8+5]*inv),
                        f2bf2(sc[s2*8+6]*inv, sc[s2*8+7]*inv) };
            *(uint4*)(lds + r * 256 + (kpos ^ sw)) = u;
        }
    }
    __syncthreads();

    // ---- MFMA: wave w owns rows [wrh*32,+32) and mn-half wnh*128 ----
    const int w = t >> 6, lane = t & 63;
    const int wrh = w >> 1, wnh = w & 1;
    const int lr = lane & 15, lg = lane >> 4;

    // W fragments (A-layout: idx=lr -> W row, k=(lg)*8+j within kc-slice)
    bf16x8 wfrag[2][4];
#pragma unroll
    for (int mi = 0; mi < 2; ++mi) {
        const int r2 = wrh * 32 + mi * 16 + lr;
        const int sw = (r2 & 7) << 4;
#pragma unroll
        for (int kc = 0; kc < 4; ++kc)
            wfrag[mi][kc] = *(const bf16x8*)(lds + r2 * 256 + ((kc * 64 + lg * 16) ^ sw));
    }

    const uint4* bmb = bmv + (size_t)b * 4096;

    f32x4 acc[2][8];
#pragma unroll
    for (int mi = 0; mi < 2; ++mi)
#pragma unroll
        for (int nt = 0; nt < 8; ++nt)
            acc[mi][nt] = (f32x4){0.f, 0.f, 0.f, 0.f};

    // D = BM_tile x W_tile^T: operand-swapped so D rows = mn, D cols = out rows.
    // Lane then owns 4 consecutive mn at one out row -> dwordx4 epilogue.
#pragma unroll
    for (int nt = 0; nt < 8; ++nt) {
        const int mn = wnh * 128 + nt * 16 + lr;
#pragma unroll
        for (int kc = 0; kc < 4; ++kc) {
            uint4 raw = bmb[(kc * 4 + lg) * 256 + mn];   // BM frag (idx=lr->mn, k slice)
            bf16x8 bfrag = *(bf16x8*)&raw;
            acc[0][nt] = __builtin_amdgcn_mfma_f32_16x16x32_bf16(bfrag, wfrag[0][kc], acc[0][nt], 0, 0, 0);
            acc[1][nt] = __builtin_amdgcn_mfma_f32_16x16x32_bf16(bfrag, wfrag[1][kc], acc[1][nt], 0, 0, 0);
        }
    }

    // ---- store: lane holds D[mn = nt*16+lg*4+reg][outrow = tile+lr] ----
    float* ob = out + (size_t)b * (ROWS * 256);
#pragma unroll
    for (int mi = 0; mi < 2; ++mi) {
        const int gr = chunk * 64 + wrh * 32 + mi * 16 + lr;
        if (gr < ROWS) {
            float* orow = ob + (size_t)gr * 256 + wnh * 128 + lg * 4;
#pragma unroll
            for (int nt = 0; nt < 8; ++nt)
                __builtin_nontemporal_store(acc[mi][nt], (f32x4*)(orow + nt * 16));
        }
    }
}

extern "C" void kernel_launch(void* const* d_in, const int* in_sizes, int n_in,
                              void* d_out, int out_size, void* d_ws, size_t ws_size,
                              hipStream_t stream) {
    const float* h_scores = (const float*)d_in[0];
    const float* v_score  = (const float*)d_in[1];
    const float* h_base   = (const float*)d_in[2];
    const float* v_base   = (const float*)d_in[3];
    float* out = (float*)d_out;
    uint4* bmv = (uint4*)d_ws;                    // B*64KB = 8MB scratch

    const int B = in_sizes[0] / SCORE_B_STRIDE;   // 128

    bm_build<<<dim3(B, 2), 256, 0, stream>>>(h_base, v_base, bmv);
    patch_gemm<<<B * NCHUNK, 256, 0, stream>>>(h_scores, v_score, bmv, out);
}